// Round 5
// baseline (223.965 us; speedup 1.0000x reference)
//
#include <hip/hip_runtime.h>

// Batched autocorrelation, X:[4096,8192] f32 -> out:[4096,64] f32.
// Per-row correlation as bf16 MFMA Gram matrices (R2/R3 formulation, proven):
//   X_i[m] = x[32 i + m];  G_d[m][n] = sum_i X_i[m] * X_{i+d}[n], d=0..2
//   R_{32q+s} = sum_{m+s<32} G_q[m][m+s] + sum_{m+s>=32} G_{q+1}[m][m+s-32]
// Centering folded in algebraically (fp32):
//   C_k = R_k - mu*(2S - P_k - Q_k) + (T-k) mu^2 ;  out = C_k / C_0
//
// R7: DRAM-burst-granularity fix. Evidence: 3.8 TB/s read plateau invariant
// under waves 16->32 (R6), VALU cuts (R3), request-count cuts (R3); wave-
// proportional below 16 (R5). All prior versions issue 256 B/instr dword
// loads from 4096 interleaved row-streams -> DRAM page thrash at ~48% peak.
// Fills / float4-copy (1 KB/instr sequential bursts) hit 87%/79%.
//   * global -> LDS staging via __builtin_amdgcn_global_load_lds width=16:
//     2 instrs stage a 2 KB chunk as two 1 KB linear bursts (linear LDS dest,
//     linear global src). Double-buffered, counted s_waitcnt vmcnt(2) in the
//     steady state (vmcnt(0) only for the last chunk).
//   * A-fragments ds_read from LDS: stride 32 floats -> bank == m,
//     2 lanes/bank across the wave = conflict-free.
//   * e8/e9 extras stay direct global dwords, prefetched 1 chunk ahead;
//     their lines are L2-resident from the DMA stream (proven free in R2/R3).
//   * Staging buffer (4 KB/wave) unions with the bf16 G-dump (6528 B/wave):
//     25.5 KB/block -> 4 blocks/CU. No cross-wave sharing, no barriers.
// Compute is bit-identical to R3 -> absmax must remain 0.0002441406.

typedef __bf16 bf16x8 __attribute__((ext_vector_type(8)));
typedef float f32x16 __attribute__((ext_vector_type(16)));
typedef unsigned int uint32;

#define T_LEN 8192
#define WPB 4                       // waves (rows) per block
#define GB_STRIDE 34                // shorts per G row (+2 pad)
#define GB_SHORTS (96 * GB_STRIDE)  // 3 matrices x 32 rows = 6528 B / wave
#define WAVE_SMEM 6528              // bytes/wave: union(staging 4096, G-dump 6528)

__device__ __forceinline__ uint32 cvtpk(float lo, float hi) { // (lo, hi) RNE
  uint32 r;
  asm("v_cvt_pk_bf16_f32 %0, %1, %2" : "=v"(r) : "v"(lo), "v"(hi));
  return r;
}
__device__ __forceinline__ short f2bf(float f) {
  uint32 u = __builtin_bit_cast(uint32, f);
  return (short)((u + 0x7fffu + ((u >> 16) & 1u)) >> 16);
}
__device__ __forceinline__ float bf2f(short h) {
  uint32 u = ((uint32)(unsigned short)h) << 16;
  return __builtin_bit_cast(float, u);
}

// One 1 KB burst: lane l reads 16 B at src+16l, lands at ldsdst+16l (linear).
__device__ __forceinline__ void stage1k(const float* src, float* ldsdst) {
  __builtin_amdgcn_global_load_lds(
      (const __attribute__((address_space(1))) void*)src,
      (__attribute__((address_space(3))) void*)ldsdst, 16, 0, 0);
}

__global__ __launch_bounds__(WPB * 64, 4)
void autocorr_kernel(const float* __restrict__ X, float* __restrict__ out, int nrows) {
  __shared__ __align__(16) char smem[WPB * WAVE_SMEM];   // 25.5 KB/block
  const int wave = threadIdx.x >> 6;
  const int lane = threadIdx.x & 63;
  const int row = blockIdx.x * WPB + wave;
  if (row >= nrows) return;               // no barriers anywhere: waves independent
  float* buf = (float*)(smem + wave * WAVE_SMEM);  // 1024 floats = 2 chunk buffers
  short* gb  = (short*)(smem + wave * WAVE_SMEM);  // reused after the main loop

  const int m = lane & 31;                // A-role row m / B-role col n
  const int sh = lane >> 5;               // K-half s
  const float* __restrict__ rb = X + (size_t)row * T_LEN;
  const float* __restrict__ ep = rb + (sh << 8) + m + 256;  // extras: ep[c<<9], +32

  f32x16 g0 = {}, g1 = {}, g2 = {};
  float ssum = 0.f;

  // ---- prologue: S(0), X(0), S(1)  (issue order matters for vmcnt counting) ----
  stage1k(rb + 4 * lane,        buf);
  stage1k(rb + 256 + 4 * lane,  buf + 256);
  float x8 = ep[0], x9 = ep[32];          // chunk-0 extras (2 vm ops)
  stage1k(rb + 512 + 4 * lane,  buf + 512);
  stage1k(rb + 768 + 4 * lane,  buf + 768);

#pragma unroll
  for (int c = 0; c < 16; ++c) {
    // steady state: leave S(c+1)'s 2 ops in flight; drain everything older.
    if (c == 15) asm volatile("s_waitcnt vmcnt(0)" ::: "memory");
    else         asm volatile("s_waitcnt vmcnt(2)" ::: "memory");

    const float* lb = buf + (c & 1) * 512 + (sh << 8) + m;
    float e0 = lb[0],   e1 = lb[32],  e2 = lb[64],  e3 = lb[96];
    float e4 = lb[128], e5 = lb[160], e6 = lb[192], e7 = lb[224];

    // prefetch extras for chunk c+1 (lines are L2-resident from the DMA stream)
    float nx8 = 0.f, nx9 = 0.f;
    if (c + 1 < 15) { nx8 = ep[(c + 1) << 9]; nx9 = ep[((c + 1) << 9) + 32]; }
    else if (c + 1 == 15) {
      if (!sh) { nx8 = ep[15 << 9]; nx9 = ep[(15 << 9) + 32]; }  // sh=1 OOB -> 0
    }

    // ---- compute chunk c (identical arithmetic to R3) ----
    ssum += ((e0 + e1) + (e2 + e3)) + ((e4 + e5) + (e6 + e7));
    uint32 u0 = cvtpk(e0, e1), u1 = cvtpk(e2, e3);
    uint32 u2 = cvtpk(e4, e5), u3 = cvtpk(e6, e7);
    uint32 u4 = cvtpk(x8, x9);
    int4 a4 = make_int4((int)u0, (int)u1, (int)u2, (int)u3);
    int4 b1;
    b1.x = (int)((u0 >> 16) | (u1 << 16));
    b1.y = (int)((u1 >> 16) | (u2 << 16));
    b1.z = (int)((u2 >> 16) | (u3 << 16));
    b1.w = (int)((u3 >> 16) | (u4 << 16));
    int4 b2 = make_int4((int)u1, (int)u2, (int)u3, (int)u4);
    bf16x8 fa = __builtin_bit_cast(bf16x8, a4);
    bf16x8 f1 = __builtin_bit_cast(bf16x8, b1);
    bf16x8 f2 = __builtin_bit_cast(bf16x8, b2);
    g0 = __builtin_amdgcn_mfma_f32_32x32x16_bf16(fa, fa, g0, 0, 0, 0);
    g1 = __builtin_amdgcn_mfma_f32_32x32x16_bf16(fa, f1, g1, 0, 0, 0);
    g2 = __builtin_amdgcn_mfma_f32_32x32x16_bf16(fa, f2, g2, 0, 0, 0);

    // ---- stage chunk c+2 into the buffer we just consumed ----
    if (c + 2 <= 15) {
      __builtin_amdgcn_sched_barrier(0);  // keep DMA issue AFTER the ds_reads above
      const float* s = rb + ((c + 2) << 9);
      float* d = buf + (c & 1) * 512;
      stage1k(s + 4 * lane,       d);
      stage1k(s + 256 + 4 * lane, d + 256);
    }
    x8 = nx8; x9 = nx9;
  }

  for (int d = 32; d > 0; d >>= 1) ssum += __shfl_xor(ssum, d, 64);

  // ---- dump G to LDS in bf16 (6.5 KB/wave; overlays the staging buffer) ----
#pragma unroll
  for (int v = 0; v < 16; ++v) {
    int rm = (v & 3) + (sh << 2) + ((v >> 2) << 3); // C/D row; col = m
    gb[(rm)      * GB_STRIDE + m] = f2bf(g0[v]);
    gb[(32 + rm) * GB_STRIDE + m] = f2bf(g1[v]);
    gb[(64 + rm) * GB_STRIDE + m] = f2bf(g2[v]);
  }

  // ---- diagonal-band sums: lane handles lag k = lane+1 ----
  int k = lane + 1;
  int s2 = k & 31, q = k >> 5;
  float ck = 0.f;
#pragma unroll 4
  for (int mm = 0; mm < 32; ++mm) {
    int ms = mm + s2;
    int dd = q + (ms >> 5);
    ck += bf2f(gb[(dd * 32 + mm) * GB_STRIDE + (ms & 31)]);
  }
  float c0 = 0.f;
#pragma unroll 4
  for (int mm = 0; mm < 32; ++mm) c0 += bf2f(gb[mm * GB_STRIDE + mm]); // broadcast

  // ---- centering correction: prefix (P_k) / suffix (Q_k) scans over lanes ----
  float P = X[(size_t)row * T_LEN + lane];
  float Q = X[(size_t)row * T_LEN + (T_LEN - 1 - lane)];
  for (int d = 1; d < 64; d <<= 1) {
    float tp = __shfl_up(P, (unsigned)d, 64);
    float tq = __shfl_up(Q, (unsigned)d, 64);
    if (lane >= d) { P += tp; Q += tq; }
  }
  float mu = ssum * (1.0f / (float)T_LEN);
  float Ck = ck - mu * (2.f * ssum - P - Q) + (float)(T_LEN - k) * mu * mu;
  float C0 = c0 - mu * 2.f * ssum + (float)T_LEN * mu * mu;
  out[(size_t)row * 64 + lane] = Ck / C0;
}

extern "C" void kernel_launch(void* const* d_in, const int* in_sizes, int n_in,
                              void* d_out, int out_size, void* d_ws, size_t ws_size,
                              hipStream_t stream) {
  const float* X = (const float*)d_in[0];
  float* out = (float*)d_out;
  int nrows = in_sizes[0] / T_LEN;  // 4096
  dim3 grid((nrows + WPB - 1) / WPB);
  autocorr_kernel<<<grid, dim3(WPB * 64), 0, stream>>>(X, out, nrows);
}

// Round 6
// 188.830 us; speedup vs baseline: 1.1861x; 1.1861x over previous
//
#include <hip/hip_runtime.h>

// Batched autocorrelation, X:[4096,8192] f32 -> out:[4096,64] f32.
// Per-row correlation as bf16 MFMA Gram matrices:
//   X_i[m] = x[32 i + m];  G_d[m][n] = sum_i X_i[m] * X_{i+d}[n], d=0..2
//   R_{32q+s} = sum_{m+s<32} G_q[m][m+s] + sum_{m+s>=32} G_{q+1}[m][m+s-32]
// Centering folded in algebraically (fp32):
//   C_k = R_k - mu*(2S - P_k - Q_k) + (T-k) mu^2 ;  out = C_k / C_0
//
// R8 = R2 revert (best measured: 188.56 us). Session findings:
//   * Kernel is ~34 us of the 188.6; 2x512 MiB harness poison-fills are a
//     fixed 154.4 us. Kernel read BW saturates at 3.8 TB/s for >=16 waves/CU,
//     invariant under 2x occupancy (R6), -60% VALU (R3), -25% requests (R3),
//     2x per-wave MLP (R5/R7) -> external ceiling: reads contend with the
//     fills' dirty-writeback drain ((134+~80 MB)/6.3 TB/s = 34 us).
//   * Depth-2 pipelines exceed the 128-reg cap of __launch_bounds__(256,4)
//     -> 60+ MB scratch spills (R4, R7). Keep depth 1.
//   * Composite graph = 1.16 GB / 188.6 us = 6.15 TB/s avg, 92-97% of the
//     mixed-stream achievable -> at the harness-level HBM roofline.
//
// R2 structure: NO LDS staging. A-fragment elements load straight from global:
//   e_j(lane m+32s, chunk c) = x[512c + 256s + 32j + m], j=0..9
// (per j each 32-lane half reads one contiguous 128 B line -> coalesced).
// Convert+pack to bf16 in-register; B1 via funnel shift, B2 via rename.
// LDS is only a 6.5 KB/wave bf16 G-dump for the diagonal-band reduction.
// Occupancy: 256 thr/block, <=128 VGPR -> 4 blocks/CU = 16 waves/CU.

typedef __bf16 bf16x8 __attribute__((ext_vector_type(8)));
typedef float f32x16 __attribute__((ext_vector_type(16)));
typedef unsigned int uint32;

#define T_LEN 8192
#define WPB 4                       // waves (rows) per block
#define GB_STRIDE 34                // shorts per G row (+2 pad)
#define GB_SHORTS (96 * GB_STRIDE)  // 3 matrices x 32 rows = 6528 B / wave

__device__ __forceinline__ uint32 pack2bf(float a, float b) { // (lo=a, hi=b) RNE
  uint32 ua = __builtin_bit_cast(uint32, a);
  uint32 ub = __builtin_bit_cast(uint32, b);
  ua += 0x7fffu + ((ua >> 16) & 1u);
  ub += 0x7fffu + ((ub >> 16) & 1u);
  return (ua >> 16) | (ub & 0xffff0000u);
}
__device__ __forceinline__ short f2bf(float f) {
  uint32 u = __builtin_bit_cast(uint32, f);
  return (short)((u + 0x7fffu + ((u >> 16) & 1u)) >> 16);
}
__device__ __forceinline__ float bf2f(short h) {
  uint32 u = ((uint32)(unsigned short)h) << 16;
  return __builtin_bit_cast(float, u);
}

__global__ __launch_bounds__(WPB * 64, 4)
void autocorr_kernel(const float* __restrict__ X, float* __restrict__ out, int nrows) {
  __shared__ short gb_all[WPB * GB_SHORTS];
  const int wave = threadIdx.x >> 6;
  const int lane = threadIdx.x & 63;
  const int row = blockIdx.x * WPB + wave;
  if (row >= nrows) return;               // no barriers anywhere: waves independent
  short* gb = gb_all + wave * GB_SHORTS;

  const int m = lane & 31;                // A-role row m / B-role col n
  const int sh = lane >> 5;               // K-half s
  const float* __restrict__ base = X + (size_t)row * T_LEN + (sh << 8) + m;

  f32x16 g0 = {}, g1 = {}, g2 = {};
  float ssum = 0.f;

#define CHUNK_BODY(PP, E8, E9)                                                  \
  {                                                                             \
    float e0 = (PP)[0],   e1 = (PP)[32],  e2 = (PP)[64],  e3 = (PP)[96];        \
    float e4 = (PP)[128], e5 = (PP)[160], e6 = (PP)[192], e7 = (PP)[224];       \
    float e8 = (E8), e9 = (E9);                                                 \
    ssum += ((e0 + e1) + (e2 + e3)) + ((e4 + e5) + (e6 + e7));                  \
    uint32 u0 = pack2bf(e0, e1), u1 = pack2bf(e2, e3), u2 = pack2bf(e4, e5);    \
    uint32 u3 = pack2bf(e6, e7), u4 = pack2bf(e8, e9);                          \
    int4 a4 = make_int4((int)u0, (int)u1, (int)u2, (int)u3);                    \
    int4 b1;                                                                    \
    b1.x = (int)((u0 >> 16) | (u1 << 16));                                      \
    b1.y = (int)((u1 >> 16) | (u2 << 16));                                      \
    b1.z = (int)((u2 >> 16) | (u3 << 16));                                      \
    b1.w = (int)((u3 >> 16) | (u4 << 16));                                      \
    int4 b2 = make_int4((int)u1, (int)u2, (int)u3, (int)u4);                    \
    bf16x8 fa = __builtin_bit_cast(bf16x8, a4);                                 \
    bf16x8 f1 = __builtin_bit_cast(bf16x8, b1);                                 \
    bf16x8 f2 = __builtin_bit_cast(bf16x8, b2);                                 \
    g0 = __builtin_amdgcn_mfma_f32_32x32x16_bf16(fa, fa, g0, 0, 0, 0);          \
    g1 = __builtin_amdgcn_mfma_f32_32x32x16_bf16(fa, f1, g1, 0, 0, 0);          \
    g2 = __builtin_amdgcn_mfma_f32_32x32x16_bf16(fa, f2, g2, 0, 0, 0);          \
  }

#pragma unroll 3
  for (int c = 0; c < 15; ++c) {
    const float* p = base + (c << 9);
    CHUNK_BODY(p, p[256], p[288])
  }
  { // last chunk: spill elements for the upper half are past end of row -> 0
    const float* p = base + (15 << 9);
    float e8s = 0.f, e9s = 0.f;
    if (!sh) { e8s = p[256]; e9s = p[288]; }   // exec-masked loads, no OOB
    CHUNK_BODY(p, e8s, e9s)
  }
#undef CHUNK_BODY

  for (int d = 32; d > 0; d >>= 1) ssum += __shfl_xor(ssum, d, 64);

  // ---- dump G to LDS in bf16 (6.5 KB/wave) ----
#pragma unroll
  for (int v = 0; v < 16; ++v) {
    int rm = (v & 3) + (sh << 2) + ((v >> 2) << 3); // C/D row; col = m
    gb[(rm)      * GB_STRIDE + m] = f2bf(g0[v]);
    gb[(32 + rm) * GB_STRIDE + m] = f2bf(g1[v]);
    gb[(64 + rm) * GB_STRIDE + m] = f2bf(g2[v]);
  }

  // ---- diagonal-band sums: lane handles lag k = lane+1 ----
  int k = lane + 1;
  int s2 = k & 31, q = k >> 5;
  float ck = 0.f;
#pragma unroll 4
  for (int mm = 0; mm < 32; ++mm) {
    int ms = mm + s2;
    int dd = q + (ms >> 5);
    ck += bf2f(gb[(dd * 32 + mm) * GB_STRIDE + (ms & 31)]);
  }
  float c0 = 0.f;
#pragma unroll 4
  for (int mm = 0; mm < 32; ++mm) c0 += bf2f(gb[mm * GB_STRIDE + mm]); // broadcast

  // ---- centering correction: prefix (P_k) / suffix (Q_k) scans over lanes ----
  float P = X[(size_t)row * T_LEN + lane];
  float Q = X[(size_t)row * T_LEN + (T_LEN - 1 - lane)];
  for (int d = 1; d < 64; d <<= 1) {
    float tp = __shfl_up(P, (unsigned)d, 64);
    float tq = __shfl_up(Q, (unsigned)d, 64);
    if (lane >= d) { P += tp; Q += tq; }
  }
  float mu = ssum * (1.0f / (float)T_LEN);
  float Ck = ck - mu * (2.f * ssum - P - Q) + (float)(T_LEN - k) * mu * mu;
  float C0 = c0 - mu * 2.f * ssum + (float)T_LEN * mu * mu;
  out[(size_t)row * 64 + lane] = Ck / C0;
}

extern "C" void kernel_launch(void* const* d_in, const int* in_sizes, int n_in,
                              void* d_out, int out_size, void* d_ws, size_t ws_size,
                              hipStream_t stream) {
  const float* X = (const float*)d_in[0];
  float* out = (float*)d_out;
  int nrows = in_sizes[0] / T_LEN;  // 4096
  dim3 grid((nrows + WPB - 1) / WPB);
  autocorr_kernel<<<grid, dim3(WPB * 64), 0, stream>>>(X, out, nrows);
}